// Round 8
// baseline (127.291 us; speedup 1.0000x reference)
//
#include <hip/hip_runtime.h>

// out = A @ x, A sparse COO (rows, cols, edge_vals), x [N,64] f32.
//
// Round-8 structure: NO global counting sort. Each scatter block owns one
// 4096-edge chunk and bucket-sorts it *within its own chunk region* of the
// pairs array (block-private streaming writes -> full 64B lines, no global
// cursors, no hist/scan kernels), emitting a u16 offset table [chunk][bucket].
// The reduce block for bucket b gathers its per-chunk runs via the table,
// stages them in LDS, then does the proven round-7 in-LDS row sort +
// REGISTER-accumulating reduce + coalesced store.
//
// Hard-won rules: inner loop accumulates in REGISTERS (LDS atomics after a
// gather serialize the DS pipe: round 6 = 550us). Pair loads staged/parallel
// (round 5 un-staged broadcast loads = 418us). Global scatter writes must be
// block-private regions (rounds 3-5: shared partial lines -> WRITE=E*64B).

#define D_FEAT   64
#define RPB      64             // rows per bucket
#define RPB_BITS 6
#define COL_BITS 17             // col < 2^17; row-in-bucket in bits [17,23)
#define COL_MASK ((1u << COL_BITS) - 1)
#define CAP      1152           // LDS pair cap per bucket (mean 800, +12 sigma)
#define NB_MAX   1600           // max buckets (1563 used)
#define NCH_MAX  400            // max chunks (306 used at 4096)

// ---------------- fallback (round-1 kernel) ----------------
__global__ void spmv_coo_kernel(const float* __restrict__ x,
                                const int* __restrict__ rows,
                                const int* __restrict__ cols,
                                const float* __restrict__ ev,
                                float* __restrict__ out,
                                int n_edges) {
    const int lane = threadIdx.x & 63;
    const int wave_global = blockIdx.x * (blockDim.x >> 6) + (threadIdx.x >> 6);
    const int n_waves = gridDim.x * (blockDim.x >> 6);
    for (int e = wave_global; e < n_edges; e += n_waves) {
        atomicAdd(&out[rows[e] * D_FEAT + lane], ev[e] * x[cols[e] * D_FEAT + lane]);
    }
}

// ------------- phase 1: per-chunk bucket sort (one block per chunk) --------
__global__ void __launch_bounds__(256) chunk_sort_kernel(
        const int* __restrict__ rows, const int* __restrict__ cols,
        const float* __restrict__ ev,
        uint2* __restrict__ pairs, unsigned short* __restrict__ table,
        int n_edges, int nb, int ch_bits) {
    __shared__ int sh_cnt[NB_MAX];
    __shared__ int sh_off[NB_MAX];
    __shared__ int sb[256];
    const int t = threadIdx.x;
    const int ch = blockIdx.x;
    const int base = ch << ch_bits;
    const int cnt = min(1 << ch_bits, n_edges - base);

    for (int i = t; i < nb; i += 256) sh_cnt[i] = 0;
    __syncthreads();
    for (int i = t; i < cnt; i += 256)
        atomicAdd(&sh_cnt[rows[base + i] >> RPB_BITS], 1);
    __syncthreads();

    // hierarchical exclusive scan over nb bins: thread t owns a contiguous
    // range [t*items, t*items+items); serial local prefix avoids per-thread
    // arrays (rule: runtime-indexed reg arrays -> scratch).
    const int items = (nb + 255) / 256;
    const int i0 = t * items;
    int s = 0;
    for (int j = 0; j < items; ++j) {
        int idx = i0 + j;
        if (idx < nb) s += sh_cnt[idx];
    }
    sb[t] = s;
    __syncthreads();
    for (int off = 1; off < 256; off <<= 1) {
        int tmp = (t >= off) ? sb[t - off] : 0;
        __syncthreads();
        sb[t] += tmp;
        __syncthreads();
    }
    int run = sb[t] - s;                      // exclusive prefix of my range
    for (int j = 0; j < items; ++j) {
        int idx = i0 + j;
        if (idx < nb) { sh_off[idx] = run; run += sh_cnt[idx]; }
    }
    __syncthreads();

    // emit table row (u16 offsets; entry nb = chunk count)
    unsigned short* trow = table + (size_t)ch * (nb + 1);
    for (int i = t; i < nb; i += 256) trow[i] = (unsigned short)sh_off[i];
    if (t == 0) trow[nb] = (unsigned short)cnt;
    __syncthreads();

    // place pass: block-private streaming region [base, base+cnt)
    for (int i = t; i < cnt; i += 256) {
        int r = rows[base + i];
        int bk = r >> RPB_BITS;
        int pos = atomicAdd(&sh_off[bk], 1);
        uint2 p;
        p.x = (unsigned)cols[base + i] | ((unsigned)(r & (RPB - 1)) << COL_BITS);
        p.y = __float_as_uint(ev[base + i]);
        pairs[base + pos] = p;
    }
}

// ------------- phase 2: per-bucket gather + in-LDS row sort + reduce -------
__global__ void __launch_bounds__(256) sort_reduce_kernel(
        const float* __restrict__ x,
        const uint2* __restrict__ pairs,
        const unsigned short* __restrict__ table,
        float* __restrict__ out,
        int n_rows, int nb, int nch, int ch_bits) {
    __shared__ uint2 buf[CAP];
    __shared__ uint2 srt[CAP];
    __shared__ int scnt[NCH_MAX];
    __shared__ int soff[NCH_MAX];
    __shared__ int sb[256];
    __shared__ int hist[RPB + 1];
    __shared__ int lcur[RPB];
    const int t = threadIdx.x;
    const int lane = t & 63;
    const int w = t >> 6;
    const int b = blockIdx.x;

    // read my table column: thread t owns contiguous chunks [t*items, ...)
    const int items = (nch + 255) / 256;
    const int c0 = t * items;
    int s = 0;
    for (int j = 0; j < items; ++j) {
        int ch = c0 + j;
        if (ch < nch) {
            const unsigned short* trow = table + (size_t)ch * (nb + 1);
            int o1 = trow[b];
            int o2 = trow[b + 1];
            scnt[ch] = o2 - o1;
            soff[ch] = o1;
            s += o2 - o1;
        }
    }
    sb[t] = s;
    __syncthreads();
    for (int off = 1; off < 256; off <<= 1) {
        int tmp = (t >= off) ? sb[t - off] : 0;
        __syncthreads();
        sb[t] += tmp;
        __syncthreads();
    }
    const int total = sb[255];
    int run = sb[t] - s;

    if (total <= CAP) {
        // stage my runs: 256 independent small load streams
        for (int j = 0; j < items; ++j) {
            int ch = c0 + j;
            if (ch < nch) {
                const int cbase = (ch << ch_bits) + soff[ch];
                const int c = scnt[ch];
                for (int k = 0; k < c; ++k) buf[run + k] = pairs[cbase + k];
                run += c;
            }
        }
        if (t <= RPB) hist[t] = 0;
        __syncthreads();
        for (int i = t; i < total; i += 256)
            atomicAdd(&hist[1 + (int)(buf[i].x >> COL_BITS)], 1);
        __syncthreads();
        if (w == 0) {
            int v = hist[1 + lane];
            for (int d = 1; d < 64; d <<= 1) {
                int n = __shfl_up(v, d);
                if (lane >= d) v += n;
            }
            hist[1 + lane] = v;
        }
        __syncthreads();
        if (w == 0) lcur[lane] = hist[lane];
        __syncthreads();
        for (int i = t; i < total; i += 256) {
            uint2 p = buf[i];
            int rl = (int)(p.x >> COL_BITS);
            int pos = atomicAdd(&lcur[rl], 1);
            srt[pos] = p;
        }
        __syncthreads();
        // register-accumulating reduce; wave w owns rows w, w+4, ...
        for (int r = w; r < RPB; r += 4) {
            const int rs = hist[r];
            const int re = hist[r + 1];
            float acc0 = 0.0f, acc1 = 0.0f;
            int j = rs;
            for (; j + 2 <= re; j += 2) {
                const uint2 p0 = srt[j];
                const uint2 p1 = srt[j + 1];
                const int cc0 = (int)(p0.x & COL_MASK);
                const int cc1 = (int)(p1.x & COL_MASK);
                acc0 += __uint_as_float(p0.y) * x[cc0 * D_FEAT + lane];
                acc1 += __uint_as_float(p1.y) * x[cc1 * D_FEAT + lane];
            }
            if (j < re) {
                const uint2 p0 = srt[j];
                const int cc0 = (int)(p0.x & COL_MASK);
                acc0 += __uint_as_float(p0.y) * x[cc0 * D_FEAT + lane];
            }
            const int row = b * RPB + r;
            if (row < n_rows) out[row * D_FEAT + lane] = acc0 + acc1;
        }
    } else {
        // overflow bucket (statistically never at mean 800, cap 1152):
        // zero owned rows, then stream runs with global atomics.
        for (int r = w; r < RPB; r += 4) {
            const int row = b * RPB + r;
            if (row < n_rows) out[row * D_FEAT + lane] = 0.0f;
        }
        __syncthreads();
        for (int ch = w; ch < nch; ch += 4) {
            const int cbase = (ch << ch_bits) + soff[ch];
            const int c = scnt[ch];
            for (int k = 0; k < c; ++k) {
                const uint2 p = pairs[cbase + k];     // broadcast load
                const int rl = (int)(p.x >> COL_BITS);
                const int cc = (int)(p.x & COL_MASK);
                const float m = __uint_as_float(p.y) * x[cc * D_FEAT + lane];
                const int row = b * RPB + rl;
                if (row < n_rows) atomicAdd(&out[row * D_FEAT + lane], m);
            }
        }
    }
}

extern "C" void kernel_launch(void* const* d_in, const int* in_sizes, int n_in,
                              void* d_out, int out_size, void* d_ws, size_t ws_size,
                              hipStream_t stream) {
    const float* x    = (const float*)d_in[1];
    const int*   rows = (const int*)d_in[2];
    const int*   cols = (const int*)d_in[3];
    const float* ev   = (const float*)d_in[4];
    float* out = (float*)d_out;
    const int n_edges = in_sizes[3];
    const int n_rows  = out_size / D_FEAT;
    const int nb = (n_rows + RPB - 1) / RPB;           // 1563 for N=100K

    // pick chunk size: prefer 4096 (306 blocks); fall back to 8192 if ws tight
    int ch_bits = 0, nch = 0;
    size_t off_table = 0;
    for (int cb = 12; cb <= 13 && ch_bits == 0; ++cb) {
        int nc = (n_edges + (1 << cb) - 1) >> cb;
        size_t pairs_b = ((size_t)nc << cb) * 8;
        size_t tab_b = (size_t)nc * (size_t)(nb + 1) * 2;
        if (nc <= NCH_MAX && ws_size >= pairs_b + tab_b) {
            ch_bits = cb; nch = nc; off_table = pairs_b;
        }
    }

    if (ch_bits == 0 || nb > NB_MAX) {
        hipMemsetAsync(d_out, 0, (size_t)out_size * sizeof(float), stream);
        spmv_coo_kernel<<<4096, 256, 0, stream>>>(x, rows, cols, ev, out, n_edges);
        return;
    }

    uint2* pairs = (uint2*)d_ws;
    unsigned short* table = (unsigned short*)((char*)d_ws + off_table);

    chunk_sort_kernel<<<nch, 256, 0, stream>>>(rows, cols, ev, pairs, table,
                                               n_edges, nb, ch_bits);
    sort_reduce_kernel<<<nb, 256, 0, stream>>>(x, pairs, table, out,
                                               n_rows, nb, nch, ch_bits);
}

// Round 9
// 114.061 us; speedup vs baseline: 1.1160x; 1.1160x over previous
//
#include <hip/hip_runtime.h>

// out = A @ x, A sparse COO (rows, cols, edge_vals), x [N,64] f32.
//
// Pipeline:
//   1. chunk_sort: one block per 4096-edge chunk, bucket-sorts it within its
//      private region of pairs[] (full-line writes, no global cursors) and
//      emits a u16 start-offset table [chunk][bucket].  (~18us measured)
//   2. transpose_table: table -> tableT [bucket][chunk] so the reduce reads
//      its per-chunk run descriptors as two contiguous 612B rows (round 8's
//      strided column reads cost +29MB FETCH across blocks).
//   3. sort_reduce: one block per 64-row bucket. 4-lane groups stage the
//      bucket's per-chunk runs into LDS in parallel -> in-LDS counting sort
//      by row -> 4-way-unrolled REGISTER-accumulating reduce -> coalesced
//      store. No global atomics.
//
// Hard-won rules: inner loop accumulates in REGISTERS (LDS atomics after a
// gather serialize the DS pipe: round 6 = 550us). Staging must be wide/
// parallel (round 8 per-thread serial runs = 109us; round 5 un-staged
// broadcast loads = 418us). Global scatter writes must be block-private
// regions (rounds 3-5: cross-XCD partial lines -> WRITE = E*64B).

#define D_FEAT   64
#define RPB      64             // rows per bucket
#define RPB_BITS 6
#define COL_BITS 17             // col < 2^17; row-in-bucket in bits [17,23)
#define COL_MASK ((1u << COL_BITS) - 1)
#define CAP      1152           // LDS pair cap per bucket (mean 800, +12 sigma)
#define NB_MAX   1600           // max buckets (1563 used)
#define NCH_MAX  400            // max chunks (306 used at 4096)

// ---------------- fallback (round-1 kernel) ----------------
__global__ void spmv_coo_kernel(const float* __restrict__ x,
                                const int* __restrict__ rows,
                                const int* __restrict__ cols,
                                const float* __restrict__ ev,
                                float* __restrict__ out,
                                int n_edges) {
    const int lane = threadIdx.x & 63;
    const int wave_global = blockIdx.x * (blockDim.x >> 6) + (threadIdx.x >> 6);
    const int n_waves = gridDim.x * (blockDim.x >> 6);
    for (int e = wave_global; e < n_edges; e += n_waves) {
        atomicAdd(&out[rows[e] * D_FEAT + lane], ev[e] * x[cols[e] * D_FEAT + lane]);
    }
}

// ------------- phase 1: per-chunk bucket sort (one block per chunk) --------
__global__ void __launch_bounds__(256) chunk_sort_kernel(
        const int* __restrict__ rows, const int* __restrict__ cols,
        const float* __restrict__ ev,
        uint2* __restrict__ pairs, unsigned short* __restrict__ table,
        int n_edges, int nb, int ch_bits) {
    __shared__ int sh_cnt[NB_MAX];
    __shared__ int sh_off[NB_MAX];
    __shared__ int sb[256];
    const int t = threadIdx.x;
    const int ch = blockIdx.x;
    const int base = ch << ch_bits;
    const int cnt = min(1 << ch_bits, n_edges - base);

    for (int i = t; i < nb; i += 256) sh_cnt[i] = 0;
    __syncthreads();
    for (int i = t; i < cnt; i += 256)
        atomicAdd(&sh_cnt[rows[base + i] >> RPB_BITS], 1);
    __syncthreads();

    // hierarchical exclusive scan over nb bins
    const int items = (nb + 255) / 256;
    const int i0 = t * items;
    int s = 0;
    for (int j = 0; j < items; ++j) {
        int idx = i0 + j;
        if (idx < nb) s += sh_cnt[idx];
    }
    sb[t] = s;
    __syncthreads();
    for (int off = 1; off < 256; off <<= 1) {
        int tmp = (t >= off) ? sb[t - off] : 0;
        __syncthreads();
        sb[t] += tmp;
        __syncthreads();
    }
    int run = sb[t] - s;
    for (int j = 0; j < items; ++j) {
        int idx = i0 + j;
        if (idx < nb) { sh_off[idx] = run; run += sh_cnt[idx]; }
    }
    __syncthreads();

    // emit table row (u16 start offsets; entry nb = chunk count)
    unsigned short* trow = table + (size_t)ch * (nb + 1);
    for (int i = t; i < nb; i += 256) trow[i] = (unsigned short)sh_off[i];
    if (t == 0) trow[nb] = (unsigned short)cnt;
    __syncthreads();

    // place pass: block-private streaming region [base, base+cnt)
    for (int i = t; i < cnt; i += 256) {
        int r = rows[base + i];
        int bk = r >> RPB_BITS;
        int pos = atomicAdd(&sh_off[bk], 1);
        uint2 p;
        p.x = (unsigned)cols[base + i] | ((unsigned)(r & (RPB - 1)) << COL_BITS);
        p.y = __float_as_uint(ev[base + i]);
        pairs[base + pos] = p;
    }
}

// ------------- phase 2: table transpose [ch][b] -> [b][ch] -----------------
#define TT 64
__global__ void __launch_bounds__(256) transpose_table_kernel(
        const unsigned short* __restrict__ table,
        unsigned short* __restrict__ tableT,
        int nch, int ncols /* nb+1 */) {
    __shared__ unsigned short tile[TT][TT + 1];
    const int r0 = blockIdx.x * TT;   // chunk tile
    const int c0 = blockIdx.y * TT;   // bucket tile
    for (int idx = threadIdx.x; idx < TT * TT; idx += 256) {
        int r = idx >> 6, c = idx & 63;
        int ch = r0 + r, b = c0 + c;
        tile[r][c] = (ch < nch && b < ncols) ? table[(size_t)ch * ncols + b] : 0;
    }
    __syncthreads();
    for (int idx = threadIdx.x; idx < TT * TT; idx += 256) {
        int b = idx >> 6, c = idx & 63;
        int gb = c0 + b, gch = r0 + c;
        if (gb < ncols && gch < nch)
            tableT[(size_t)gb * nch + gch] = tile[c][b];
    }
}

// ------------- phase 3: per-bucket stage + in-LDS row sort + reduce --------
__global__ void __launch_bounds__(256) sort_reduce_kernel(
        const float* __restrict__ x,
        const uint2* __restrict__ pairs,
        const unsigned short* __restrict__ table,
        const unsigned short* __restrict__ tableT,
        float* __restrict__ out,
        int n_rows, int nb, int nch, int ch_bits, int use_tt) {
    __shared__ uint2 buf[CAP];
    __shared__ uint2 srt[CAP];
    __shared__ int scnt[NCH_MAX];
    __shared__ int soff[NCH_MAX];
    __shared__ int sstart[NCH_MAX];
    __shared__ int sb[256];
    __shared__ int hist[RPB + 1];
    __shared__ int lcur[RPB];
    const int t = threadIdx.x;
    const int lane = t & 63;
    const int w = t >> 6;
    const int b = blockIdx.x;

    // read run descriptors for my bucket; thread t owns chunks [t*items, ...)
    const int items = (nch + 255) / 256;
    const int c0 = t * items;
    int s = 0;
    if (use_tt) {
        const unsigned short* rowB0 = tableT + (size_t)b * nch;
        const unsigned short* rowB1 = tableT + (size_t)(b + 1) * nch;
        for (int j = 0; j < items; ++j) {
            int ch = c0 + j;
            if (ch < nch) {
                int o1 = rowB0[ch];
                int o2 = rowB1[ch];
                scnt[ch] = o2 - o1;
                soff[ch] = o1;
                s += o2 - o1;
            }
        }
    } else {
        for (int j = 0; j < items; ++j) {
            int ch = c0 + j;
            if (ch < nch) {
                const unsigned short* trow = table + (size_t)ch * (nb + 1) + b;
                int o1 = trow[0];
                int o2 = trow[1];
                scnt[ch] = o2 - o1;
                soff[ch] = o1;
                s += o2 - o1;
            }
        }
    }
    sb[t] = s;
    __syncthreads();
    for (int off = 1; off < 256; off <<= 1) {
        int tmp = (t >= off) ? sb[t - off] : 0;
        __syncthreads();
        sb[t] += tmp;
        __syncthreads();
    }
    const int total = sb[255];
    int run = sb[t] - s;
    for (int j = 0; j < items; ++j) {
        int ch = c0 + j;
        if (ch < nch) { sstart[ch] = run; run += scnt[ch]; }
    }
    if (t <= RPB) hist[t] = 0;
    __syncthreads();

    if (total <= CAP) {
        // stage runs: 4-lane group per chunk -> many parallel line fetches
        const int g = t >> 2;       // 0..63
        const int sl = t & 3;
        for (int ch = g; ch < nch; ch += 64) {
            const int c = scnt[ch];
            const int cbase = (ch << ch_bits) + soff[ch];
            const int dst = sstart[ch];
            for (int k = sl; k < c; k += 4) {
                uint2 p = pairs[cbase + k];
                buf[dst + k] = p;
                atomicAdd(&hist[1 + (int)(p.x >> COL_BITS)], 1);
            }
        }
        __syncthreads();
        // wave 0: inclusive shfl-scan of hist[1..RPB] -> row_ptr
        if (w == 0) {
            int v = hist[1 + lane];
            for (int d = 1; d < 64; d <<= 1) {
                int n = __shfl_up(v, d);
                if (lane >= d) v += n;
            }
            hist[1 + lane] = v;
        }
        __syncthreads();
        if (w == 0) lcur[lane] = hist[lane];
        __syncthreads();
        // in-LDS scatter into row-sorted order
        for (int i = t; i < total; i += 256) {
            uint2 p = buf[i];
            int rl = (int)(p.x >> COL_BITS);
            int pos = atomicAdd(&lcur[rl], 1);
            srt[pos] = p;
        }
        __syncthreads();
        // 4-way-unrolled register reduce; wave w owns rows w, w+4, ...
        for (int r = w; r < RPB; r += 4) {
            const int rs = hist[r];
            const int re = hist[r + 1];
            float a0 = 0.0f, a1 = 0.0f, a2 = 0.0f, a3 = 0.0f;
            int j = rs;
            for (; j + 4 <= re; j += 4) {
                const uint2 p0 = srt[j];
                const uint2 p1 = srt[j + 1];
                const uint2 p2 = srt[j + 2];
                const uint2 p3 = srt[j + 3];
                a0 += __uint_as_float(p0.y) * x[(int)(p0.x & COL_MASK) * D_FEAT + lane];
                a1 += __uint_as_float(p1.y) * x[(int)(p1.x & COL_MASK) * D_FEAT + lane];
                a2 += __uint_as_float(p2.y) * x[(int)(p2.x & COL_MASK) * D_FEAT + lane];
                a3 += __uint_as_float(p3.y) * x[(int)(p3.x & COL_MASK) * D_FEAT + lane];
            }
            for (; j < re; ++j) {
                const uint2 p0 = srt[j];
                a0 += __uint_as_float(p0.y) * x[(int)(p0.x & COL_MASK) * D_FEAT + lane];
            }
            const int row = b * RPB + r;
            if (row < n_rows) out[row * D_FEAT + lane] = (a0 + a1) + (a2 + a3);
        }
    } else {
        // overflow bucket (statistically never at mean 800, cap 1152)
        for (int r = w; r < RPB; r += 4) {
            const int row = b * RPB + r;
            if (row < n_rows) out[row * D_FEAT + lane] = 0.0f;
        }
        __syncthreads();
        for (int ch = w; ch < nch; ch += 4) {
            const int cbase = (ch << ch_bits) + soff[ch];
            const int c = scnt[ch];
            for (int k = 0; k < c; ++k) {
                const uint2 p = pairs[cbase + k];
                const int rl = (int)(p.x >> COL_BITS);
                const int cc = (int)(p.x & COL_MASK);
                const float m = __uint_as_float(p.y) * x[cc * D_FEAT + lane];
                const int row = b * RPB + rl;
                if (row < n_rows) atomicAdd(&out[row * D_FEAT + lane], m);
            }
        }
    }
}

extern "C" void kernel_launch(void* const* d_in, const int* in_sizes, int n_in,
                              void* d_out, int out_size, void* d_ws, size_t ws_size,
                              hipStream_t stream) {
    const float* x    = (const float*)d_in[1];
    const int*   rows = (const int*)d_in[2];
    const int*   cols = (const int*)d_in[3];
    const float* ev   = (const float*)d_in[4];
    float* out = (float*)d_out;
    const int n_edges = in_sizes[3];
    const int n_rows  = out_size / D_FEAT;
    const int n_cols  = in_sizes[1] / D_FEAT;
    const int nb = (n_rows + RPB - 1) / RPB;           // 1563 for N=100K

    // pick chunk size (prefer 4096); decide if tableT fits too
    int ch_bits = 0, nch = 0, use_tt = 0;
    size_t off_table = 0, off_tableT = 0;
    for (int cb = 12; cb <= 13 && ch_bits == 0; ++cb) {
        int nc = (n_edges + (1 << cb) - 1) >> cb;
        size_t pairs_b = ((size_t)nc << cb) * 8;
        size_t tab_b = (size_t)nc * (size_t)(nb + 1) * 2;
        if (nc <= NCH_MAX && ws_size >= pairs_b + tab_b) {
            ch_bits = cb; nch = nc;
            off_table = pairs_b;
            if (ws_size >= pairs_b + 2 * tab_b) {
                use_tt = 1;
                off_tableT = pairs_b + tab_b;
            }
        }
    }

    if (ch_bits == 0 || nb > NB_MAX || n_cols > (1 << COL_BITS) ||
        n_rows > (1 << COL_BITS)) {
        hipMemsetAsync(d_out, 0, (size_t)out_size * sizeof(float), stream);
        spmv_coo_kernel<<<4096, 256, 0, stream>>>(x, rows, cols, ev, out, n_edges);
        return;
    }

    uint2* pairs = (uint2*)d_ws;
    unsigned short* table  = (unsigned short*)((char*)d_ws + off_table);
    unsigned short* tableT = (unsigned short*)((char*)d_ws + off_tableT);

    chunk_sort_kernel<<<nch, 256, 0, stream>>>(rows, cols, ev, pairs, table,
                                               n_edges, nb, ch_bits);
    if (use_tt) {
        dim3 tg((nch + TT - 1) / TT, (nb + 1 + TT - 1) / TT);
        transpose_table_kernel<<<tg, 256, 0, stream>>>(table, tableT, nch, nb + 1);
    }
    sort_reduce_kernel<<<nb, 256, 0, stream>>>(x, pairs, table, tableT, out,
                                               n_rows, nb, nch, ch_bits, use_tt);
}

// Round 10
// 91.453 us; speedup vs baseline: 1.3919x; 1.2472x over previous
//
#include <hip/hip_runtime.h>

// out = A @ x, A sparse COO (rows, cols, edge_vals), x [N,64] f32.
//
// Pipeline:
//   1. chunk_sort: one block per 4096-edge chunk, bucket-sorts it within its
//      private region of pairs[] (full-line writes, no global cursors) and
//      emits a u16 start-offset table [chunk][bucket].
//   2. transpose_table: table -> tableT [bucket][chunk] (contiguous reads in
//      the reduce; round 8's strided column reads cost +29MB FETCH).
//   3. sort_reduce: one block per 64-row bucket. Stage runs into LDS (pure
//      copy, NO atomics in the staging loop) -> LDS-only histogram pass ->
//      shfl scan -> u16 index sort -> two-rows-in-flight 4+4-unrolled
//      REGISTER reduce (8 outstanding gathers/wave) -> coalesced store.
//
// Hard-won rules: inner loops accumulate in REGISTERS; never put an LDS
// atomic data-dependent on a global load inside a hot loop (DS pipe
// serializes behind vmcnt: round 6 = 550us); staging must be wide/parallel
// (round 8 serial runs = 109us); global scatter writes must be block-private
// regions (rounds 3-5: cross-XCD partial lines -> WRITE = E*64B).
// LDS diet: u16 sort-indices + u16 descriptors -> 15.7KB -> 8 blocks/CU
// (round 9's 25KB capped occupancy at 6 blocks/CU, 40%).

#define D_FEAT   64
#define RPB      64             // rows per bucket
#define RPB_BITS 6
#define COL_BITS 17             // col < 2^17; row-in-bucket in bits [17,23)
#define COL_MASK ((1u << COL_BITS) - 1)
#define CAP      1152           // LDS pair cap per bucket (mean 800, +12 sigma)
#define NB_MAX   1600           // max buckets (1563 used)
#define NCH_MAX  400            // max chunks (306 used at 4096)

// ---------------- fallback (round-1 kernel) ----------------
__global__ void spmv_coo_kernel(const float* __restrict__ x,
                                const int* __restrict__ rows,
                                const int* __restrict__ cols,
                                const float* __restrict__ ev,
                                float* __restrict__ out,
                                int n_edges) {
    const int lane = threadIdx.x & 63;
    const int wave_global = blockIdx.x * (blockDim.x >> 6) + (threadIdx.x >> 6);
    const int n_waves = gridDim.x * (blockDim.x >> 6);
    for (int e = wave_global; e < n_edges; e += n_waves) {
        atomicAdd(&out[rows[e] * D_FEAT + lane], ev[e] * x[cols[e] * D_FEAT + lane]);
    }
}

// ------------- phase 1: per-chunk bucket sort (one block per chunk) --------
__global__ void __launch_bounds__(256) chunk_sort_kernel(
        const int* __restrict__ rows, const int* __restrict__ cols,
        const float* __restrict__ ev,
        uint2* __restrict__ pairs, unsigned short* __restrict__ table,
        int n_edges, int nb, int ch_bits) {
    __shared__ int sh_cnt[NB_MAX];
    __shared__ int sh_off[NB_MAX];
    __shared__ int sb[256];
    const int t = threadIdx.x;
    const int ch = blockIdx.x;
    const int base = ch << ch_bits;
    const int cnt = min(1 << ch_bits, n_edges - base);

    for (int i = t; i < nb; i += 256) sh_cnt[i] = 0;
    __syncthreads();
    for (int i = t; i < cnt; i += 256)
        atomicAdd(&sh_cnt[rows[base + i] >> RPB_BITS], 1);
    __syncthreads();

    // hierarchical exclusive scan over nb bins
    const int items = (nb + 255) / 256;
    const int i0 = t * items;
    int s = 0;
    for (int j = 0; j < items; ++j) {
        int idx = i0 + j;
        if (idx < nb) s += sh_cnt[idx];
    }
    sb[t] = s;
    __syncthreads();
    for (int off = 1; off < 256; off <<= 1) {
        int tmp = (t >= off) ? sb[t - off] : 0;
        __syncthreads();
        sb[t] += tmp;
        __syncthreads();
    }
    int run = sb[t] - s;
    for (int j = 0; j < items; ++j) {
        int idx = i0 + j;
        if (idx < nb) { sh_off[idx] = run; run += sh_cnt[idx]; }
    }
    __syncthreads();

    // emit table row (u16 start offsets; entry nb = chunk count)
    unsigned short* trow = table + (size_t)ch * (nb + 1);
    for (int i = t; i < nb; i += 256) trow[i] = (unsigned short)sh_off[i];
    if (t == 0) trow[nb] = (unsigned short)cnt;
    __syncthreads();

    // place pass: block-private streaming region [base, base+cnt)
    for (int i = t; i < cnt; i += 256) {
        int r = rows[base + i];
        int bk = r >> RPB_BITS;
        int pos = atomicAdd(&sh_off[bk], 1);
        uint2 p;
        p.x = (unsigned)cols[base + i] | ((unsigned)(r & (RPB - 1)) << COL_BITS);
        p.y = __float_as_uint(ev[base + i]);
        pairs[base + pos] = p;
    }
}

// ------------- phase 2: table transpose [ch][b] -> [b][ch] -----------------
#define TT 64
__global__ void __launch_bounds__(256) transpose_table_kernel(
        const unsigned short* __restrict__ table,
        unsigned short* __restrict__ tableT,
        int nch, int ncols /* nb+1 */) {
    __shared__ unsigned short tile[TT][TT + 1];
    const int r0 = blockIdx.x * TT;   // chunk tile
    const int c0 = blockIdx.y * TT;   // bucket tile
    for (int idx = threadIdx.x; idx < TT * TT; idx += 256) {
        int r = idx >> 6, c = idx & 63;
        int ch = r0 + r, b = c0 + c;
        tile[r][c] = (ch < nch && b < ncols) ? table[(size_t)ch * ncols + b] : 0;
    }
    __syncthreads();
    for (int idx = threadIdx.x; idx < TT * TT; idx += 256) {
        int b = idx >> 6, c = idx & 63;
        int gb = c0 + b, gch = r0 + c;
        if (gb < ncols && gch < nch)
            tableT[(size_t)gb * nch + gch] = tile[c][b];
    }
}

// ------------- phase 3: per-bucket stage + u16 index sort + reduce ---------
__global__ void __launch_bounds__(256) sort_reduce_kernel(
        const float* __restrict__ x,
        const uint2* __restrict__ pairs,
        const unsigned short* __restrict__ table,
        const unsigned short* __restrict__ tableT,
        float* __restrict__ out,
        int n_rows, int nb, int nch, int ch_bits, int use_tt) {
    __shared__ uint2 buf[CAP];                 // 9.2 KB staged pairs
    __shared__ unsigned short srt16[CAP];      // 2.3 KB sorted indices
    __shared__ unsigned short scnt16[NCH_MAX]; // 0.8 KB
    __shared__ unsigned short soff16[NCH_MAX]; // 0.8 KB
    __shared__ unsigned short sst16[NCH_MAX];  // 0.8 KB LDS dst of each run
    __shared__ int sb[256];                    // 1 KB
    __shared__ int hist[RPB + 1];
    __shared__ int lcur[RPB];
    const int t = threadIdx.x;
    const int lane = t & 63;
    const int w = t >> 6;
    const int b = blockIdx.x;

    // read run descriptors; thread t owns chunks [t*items, t*items+items)
    const int items = (nch + 255) / 256;
    const int c0 = t * items;
    int s = 0;
    if (use_tt) {
        const unsigned short* rowB0 = tableT + (size_t)b * nch;
        const unsigned short* rowB1 = tableT + (size_t)(b + 1) * nch;
        for (int j = 0; j < items; ++j) {
            int ch = c0 + j;
            if (ch < nch) {
                int o1 = rowB0[ch];
                int o2 = rowB1[ch];
                scnt16[ch] = (unsigned short)(o2 - o1);
                soff16[ch] = (unsigned short)o1;
                s += o2 - o1;
            }
        }
    } else {
        for (int j = 0; j < items; ++j) {
            int ch = c0 + j;
            if (ch < nch) {
                const unsigned short* trow = table + (size_t)ch * (nb + 1) + b;
                int o1 = trow[0];
                int o2 = trow[1];
                scnt16[ch] = (unsigned short)(o2 - o1);
                soff16[ch] = (unsigned short)o1;
                s += o2 - o1;
            }
        }
    }
    sb[t] = s;
    __syncthreads();
    for (int off = 1; off < 256; off <<= 1) {
        int tmp = (t >= off) ? sb[t - off] : 0;
        __syncthreads();
        sb[t] += tmp;
        __syncthreads();
    }
    const int total = sb[255];
    int run = sb[t] - s;
    for (int j = 0; j < items; ++j) {
        int ch = c0 + j;
        if (ch < nch) { sst16[ch] = (unsigned short)run; run += scnt16[ch]; }
    }
    if (t <= RPB) hist[t] = 0;
    __syncthreads();

    if (total <= CAP) {
        // stage runs: 4-lane group per chunk, PURE COPY (no LDS atomics here)
        const int g = t >> 2;       // 0..63
        const int sl = t & 3;
        for (int ch = g; ch < nch; ch += 64) {
            const int c = scnt16[ch];
            const int cbase = (ch << ch_bits) + soff16[ch];
            const int dst = sst16[ch];
            for (int k = sl; k < c; k += 4)
                buf[dst + k] = pairs[cbase + k];
        }
        __syncthreads();
        // LDS-only histogram pass
        const unsigned* bufx = (const unsigned*)buf;
        for (int i = t; i < total; i += 256)
            atomicAdd(&hist[1 + (int)(bufx[2 * i] >> COL_BITS)], 1);
        __syncthreads();
        // wave 0: inclusive shfl-scan of hist[1..RPB] -> row_ptr
        if (w == 0) {
            int v = hist[1 + lane];
            for (int d = 1; d < 64; d <<= 1) {
                int n = __shfl_up(v, d);
                if (lane >= d) v += n;
            }
            hist[1 + lane] = v;
        }
        __syncthreads();
        if (w == 0) lcur[lane] = hist[lane];
        __syncthreads();
        // u16 index sort (LDS-only)
        for (int i = t; i < total; i += 256) {
            int rl = (int)(bufx[2 * i] >> COL_BITS);
            int pos = atomicAdd(&lcur[rl], 1);
            srt16[pos] = (unsigned short)i;
        }
        __syncthreads();
        // reduce: wave w owns rows w+4m; process TWO rows concurrently,
        // 4-wide each -> 8 independent gathers in flight.
        const float* xl = x + lane;
        for (int q = 0; q < RPB / 8; ++q) {
            const int rA = w + 8 * q;
            const int rB = rA + 4;
            int jA = hist[rA], eA = hist[rA + 1];
            int jB = hist[rB], eB = hist[rB + 1];
            float aA0 = 0.0f, aA1 = 0.0f, aB0 = 0.0f, aB1 = 0.0f;
            while (jA + 4 <= eA && jB + 4 <= eB) {
                const uint2 pa0 = buf[srt16[jA]];
                const uint2 pa1 = buf[srt16[jA + 1]];
                const uint2 pa2 = buf[srt16[jA + 2]];
                const uint2 pa3 = buf[srt16[jA + 3]];
                const uint2 pb0 = buf[srt16[jB]];
                const uint2 pb1 = buf[srt16[jB + 1]];
                const uint2 pb2 = buf[srt16[jB + 2]];
                const uint2 pb3 = buf[srt16[jB + 3]];
                aA0 += __uint_as_float(pa0.y) * xl[(int)(pa0.x & COL_MASK) * D_FEAT];
                aA1 += __uint_as_float(pa1.y) * xl[(int)(pa1.x & COL_MASK) * D_FEAT];
                aA0 += __uint_as_float(pa2.y) * xl[(int)(pa2.x & COL_MASK) * D_FEAT];
                aA1 += __uint_as_float(pa3.y) * xl[(int)(pa3.x & COL_MASK) * D_FEAT];
                aB0 += __uint_as_float(pb0.y) * xl[(int)(pb0.x & COL_MASK) * D_FEAT];
                aB1 += __uint_as_float(pb1.y) * xl[(int)(pb1.x & COL_MASK) * D_FEAT];
                aB0 += __uint_as_float(pb2.y) * xl[(int)(pb2.x & COL_MASK) * D_FEAT];
                aB1 += __uint_as_float(pb3.y) * xl[(int)(pb3.x & COL_MASK) * D_FEAT];
                jA += 4; jB += 4;
            }
            while (jA + 2 <= eA) {
                const uint2 p0 = buf[srt16[jA]];
                const uint2 p1 = buf[srt16[jA + 1]];
                aA0 += __uint_as_float(p0.y) * xl[(int)(p0.x & COL_MASK) * D_FEAT];
                aA1 += __uint_as_float(p1.y) * xl[(int)(p1.x & COL_MASK) * D_FEAT];
                jA += 2;
            }
            while (jB + 2 <= eB) {
                const uint2 p0 = buf[srt16[jB]];
                const uint2 p1 = buf[srt16[jB + 1]];
                aB0 += __uint_as_float(p0.y) * xl[(int)(p0.x & COL_MASK) * D_FEAT];
                aB1 += __uint_as_float(p1.y) * xl[(int)(p1.x & COL_MASK) * D_FEAT];
                jB += 2;
            }
            if (jA < eA) {
                const uint2 p0 = buf[srt16[jA]];
                aA0 += __uint_as_float(p0.y) * xl[(int)(p0.x & COL_MASK) * D_FEAT];
            }
            if (jB < eB) {
                const uint2 p0 = buf[srt16[jB]];
                aB0 += __uint_as_float(p0.y) * xl[(int)(p0.x & COL_MASK) * D_FEAT];
            }
            const int rowA = b * RPB + rA;
            const int rowB = b * RPB + rB;
            if (rowA < n_rows) out[rowA * D_FEAT + lane] = aA0 + aA1;
            if (rowB < n_rows) out[rowB * D_FEAT + lane] = aB0 + aB1;
        }
    } else {
        // overflow bucket (statistically never at mean 800, cap 1152)
        for (int r = w; r < RPB; r += 4) {
            const int row = b * RPB + r;
            if (row < n_rows) out[row * D_FEAT + lane] = 0.0f;
        }
        __syncthreads();
        for (int ch = w; ch < nch; ch += 4) {
            const int cbase = (ch << ch_bits) + soff16[ch];
            const int c = scnt16[ch];
            for (int k = 0; k < c; ++k) {
                const uint2 p = pairs[cbase + k];
                const int rl = (int)(p.x >> COL_BITS);
                const int cc = (int)(p.x & COL_MASK);
                const float m = __uint_as_float(p.y) * x[cc * D_FEAT + lane];
                const int row = b * RPB + rl;
                if (row < n_rows) atomicAdd(&out[row * D_FEAT + lane], m);
            }
        }
    }
}

extern "C" void kernel_launch(void* const* d_in, const int* in_sizes, int n_in,
                              void* d_out, int out_size, void* d_ws, size_t ws_size,
                              hipStream_t stream) {
    const float* x    = (const float*)d_in[1];
    const int*   rows = (const int*)d_in[2];
    const int*   cols = (const int*)d_in[3];
    const float* ev   = (const float*)d_in[4];
    float* out = (float*)d_out;
    const int n_edges = in_sizes[3];
    const int n_rows  = out_size / D_FEAT;
    const int n_cols  = in_sizes[1] / D_FEAT;
    const int nb = (n_rows + RPB - 1) / RPB;           // 1563 for N=100K

    // pick chunk size (prefer 4096); decide if tableT fits too
    int ch_bits = 0, nch = 0, use_tt = 0;
    size_t off_table = 0, off_tableT = 0;
    for (int cb = 12; cb <= 13 && ch_bits == 0; ++cb) {
        int nc = (n_edges + (1 << cb) - 1) >> cb;
        size_t pairs_b = ((size_t)nc << cb) * 8;
        size_t tab_b = (size_t)nc * (size_t)(nb + 1) * 2;
        if (nc <= NCH_MAX && ws_size >= pairs_b + tab_b) {
            ch_bits = cb; nch = nc;
            off_table = pairs_b;
            if (ws_size >= pairs_b + 2 * tab_b) {
                use_tt = 1;
                off_tableT = pairs_b + tab_b;
            }
        }
    }

    if (ch_bits == 0 || nb > NB_MAX || n_cols > (1 << COL_BITS) ||
        n_rows > (1 << COL_BITS)) {
        hipMemsetAsync(d_out, 0, (size_t)out_size * sizeof(float), stream);
        spmv_coo_kernel<<<4096, 256, 0, stream>>>(x, rows, cols, ev, out, n_edges);
        return;
    }

    uint2* pairs = (uint2*)d_ws;
    unsigned short* table  = (unsigned short*)((char*)d_ws + off_table);
    unsigned short* tableT = (unsigned short*)((char*)d_ws + off_tableT);

    chunk_sort_kernel<<<nch, 256, 0, stream>>>(rows, cols, ev, pairs, table,
                                               n_edges, nb, ch_bits);
    if (use_tt) {
        dim3 tg((nch + TT - 1) / TT, (nb + 1 + TT - 1) / TT);
        transpose_table_kernel<<<tg, 256, 0, stream>>>(table, tableT, nch, nb + 1);
    }
    sort_reduce_kernel<<<nb, 256, 0, stream>>>(x, pairs, table, tableT, out,
                                               n_rows, nb, nch, ch_bits, use_tt);
}